// Round 5
// baseline (617.536 us; speedup 1.0000x reference)
//
#include <hip/hip_runtime.h>
#include <math.h>
#include <stdint.h>

// UpsampleFlow3: fused exact 5-NN + softmax(-dist) + weighted flow sum.
// B=4, N=16384, M=4096, K=5, fp32.
//
// Round-5: deterministic grid search. r4's validation launch PASSED (grid
// prep + u64-key selection + epilogue are correct) but replays diverged and
// ran 7x slow -- the only nondeterministic machinery was the cross-wave
// LDS-atomicMin early stop. Removed: each slice now stops on its OWN
// slice-local 5th-best (conservative upper bound of global d5), giving a
// fully deterministic, replay-stable trip count and bit-stable output.

typedef unsigned int u32;
typedef unsigned long long u64;

#define KNN 5
#define G 16
#define G3 (G * G * G)            // 4096
#define SBLOCK 512                // 4 query-groups x 2 slices
#define GROUPS_PER_BLOCK 4

__device__ __forceinline__ float get_inv_sigma(const int* __restrict__ rf) {
    const int ri = rf[0];
    const float sigma = (ri >= 1 && ri <= 1000000) ? (float)ri : __int_as_float(ri);
    return 1.0f / sigma;          // INITIAL_RADIUS = 1.0
}

// identical cell mapping everywhere (count / scatter / search)
__device__ __forceinline__ void cell_of(float x, float y, float z,
                                        const float4 o, const float invh,
                                        int& cx, int& cy, int& cz) {
    cx = (int)floorf((x - o.x) * invh);
    cy = (int)floorf((y - o.y) * invh);
    cz = (int)floorf((z - o.z) * invh);
    cx = min(max(cx, 0), G - 1);
    cy = min(max(cy, 0), G - 1);
    cz = min(max(cz, 0), G - 1);
}

// ---------------- prep kernels (validated by r4's first-launch pass) ----------------

__global__ __launch_bounds__(256)
void zero_bbox_kernel(const float* __restrict__ sxyz, const int* __restrict__ rf,
                      int M, float4* __restrict__ bbox,
                      u32* __restrict__ meta, u32* __restrict__ cursor) {
    const int b = blockIdx.x, tid = threadIdx.x;
    u32* mb = meta + b * G3;
    u32* cb = cursor + b * G3;
    for (int i = tid; i < G3; i += 256) { mb[i] = 0u; cb[i] = 0u; }

    const float inv = get_inv_sigma(rf);
    const float* sb = sxyz + (size_t)b * 3 * M;
    float mnx = 1e30f, mny = 1e30f, mnz = 1e30f;
    float mxx = -1e30f, mxy = -1e30f, mxz = -1e30f;
    for (int i = tid; i < M; i += 256) {
        const float x = sb[i] * inv, y = sb[M + i] * inv, z = sb[2 * M + i] * inv;
        mnx = fminf(mnx, x); mxx = fmaxf(mxx, x);
        mny = fminf(mny, y); mxy = fmaxf(mxy, y);
        mnz = fminf(mnz, z); mxz = fmaxf(mxz, z);
    }
    __shared__ float red[6][256];
    red[0][tid] = mnx; red[1][tid] = mny; red[2][tid] = mnz;
    red[3][tid] = mxx; red[4][tid] = mxy; red[5][tid] = mxz;
    __syncthreads();
    for (int s = 128; s > 0; s >>= 1) {
        if (tid < s) {
            red[0][tid] = fminf(red[0][tid], red[0][tid + s]);
            red[1][tid] = fminf(red[1][tid], red[1][tid + s]);
            red[2][tid] = fminf(red[2][tid], red[2][tid + s]);
            red[3][tid] = fmaxf(red[3][tid], red[3][tid + s]);
            red[4][tid] = fmaxf(red[4][tid], red[4][tid + s]);
            red[5][tid] = fmaxf(red[5][tid], red[5][tid + s]);
        }
        __syncthreads();
    }
    if (tid == 0) {
        const float ox = red[0][0], oy = red[1][0], oz = red[2][0];
        const float ex = red[3][0] - ox, ey = red[4][0] - oy, ez = red[5][0] - oz;
        const float ext = fmaxf(fmaxf(ex, ey), ez);
        const float h = ext * (1.0f + 2e-5f) / (float)G + 1e-20f;
        bbox[2 * b + 0] = make_float4(ox, oy, oz, h);
        bbox[2 * b + 1] = make_float4(1.0f / h, 0.f, 0.f, 0.f);
    }
}

__global__ __launch_bounds__(256)
void count_kernel(const float* __restrict__ sxyz, const int* __restrict__ rf,
                  int M, int total, const float4* __restrict__ bbox,
                  u32* __restrict__ meta) {
    const int t = blockIdx.x * 256 + threadIdx.x;
    if (t >= total) return;
    const int b = t / M, m = t - b * M;
    const float inv = get_inv_sigma(rf);
    const float* sb = sxyz + (size_t)b * 3 * M;
    const float x = sb[m] * inv, y = sb[M + m] * inv, z = sb[2 * M + m] * inv;
    const float4 o = bbox[2 * b];
    const float invh = bbox[2 * b + 1].x;
    int cx, cy, cz; cell_of(x, y, z, o, invh, cx, cy, cz);
    atomicAdd(&meta[b * G3 + (cz * G + cy) * G + cx], 1u);
}

__global__ __launch_bounds__(256)
void scan_kernel(u32* __restrict__ meta, u32* __restrict__ cursor) {
    const int b = blockIdx.x, tid = threadIdx.x;
    u32* mb = meta + b * G3;
    u32* cb = cursor + b * G3;
    __shared__ u32 tmp[256];
    __shared__ u32 carry;
    if (tid == 0) carry = 0u;
    __syncthreads();
    for (int base = 0; base < G3; base += 256) {       // G3 % 256 == 0
        const u32 c = mb[base + tid];
        tmp[tid] = c;
        __syncthreads();
        for (int s = 1; s < 256; s <<= 1) {
            u32 v = (tid >= s) ? tmp[tid - s] : 0u;
            __syncthreads();
            tmp[tid] += v;
            __syncthreads();
        }
        const u32 incl = tmp[tid];
        const u32 start = carry + incl - c;            // exclusive
        mb[base + tid] = (start << 13) | c;            // start,c <= 4096 fit 13b
        cb[base + tid] = start;
        __syncthreads();
        if (tid == 255) carry += tmp[255];
        __syncthreads();
    }
}

__global__ __launch_bounds__(256)
void scatter_kernel(const float* __restrict__ sxyz, const int* __restrict__ rf,
                    int M, int total, const float4* __restrict__ bbox,
                    u32* __restrict__ cursor, float4* __restrict__ pts) {
    const int t = blockIdx.x * 256 + threadIdx.x;
    if (t >= total) return;
    const int b = t / M, m = t - b * M;
    const float inv = get_inv_sigma(rf);
    const float* sb = sxyz + (size_t)b * 3 * M;
    const float x = sb[m] * inv, y = sb[M + m] * inv, z = sb[2 * M + m] * inv;
    const float4 o = bbox[2 * b];
    const float invh = bbox[2 * b + 1].x;
    int cx, cy, cz; cell_of(x, y, z, o, invh, cx, cy, cz);
    const u32 pos = atomicAdd(&cursor[b * G3 + (cz * G + cy) * G + cx], 1u);
    pts[(size_t)b * M + pos] = make_float4(x, y, z, __uint_as_float((u32)m));
}

// ---------------- search (deterministic) ----------------

#define CEK_FULL(k, c) { const bool sw_ = (c) < (k); const u64 mn_ = sw_ ? (c) : (k); \
                         const u64 mx_ = sw_ ? (k) : (c); (k) = mn_; (c) = mx_; }
#define CEK_LAST(k, c) { (k) = ((c) < (k)) ? (c) : (k); }

#define PROC_CAND(p) {                                                        \
    float t_ = qx * (p).x; t_ = fmaf(qy, (p).y, t_); t_ = fmaf(qz, (p).z, t_);\
    const float pw_ = fmaf((p).x, (p).x, fmaf((p).y, (p).y, (p).z * (p).z));  \
    const float dc_ = fmaxf(fmaf(-2.0f, t_, qq + pw_), 1e-12f);               \
    u64 c_ = ((u64)__float_as_uint(dc_) << 32) | (u64)__float_as_uint((p).w); \
    CEK_FULL(k0, c_) CEK_FULL(k1, c_) CEK_FULL(k2, c_) CEK_FULL(k3, c_)       \
    CEK_LAST(k4, c_) }

// key init: (FLT_MAX, idx 0) -- in-bounds gather even in pathological merges
#define KEY_INIT (((u64)0x7F7FFFFFu) << 32)

__global__ __launch_bounds__(SBLOCK)
void grid_search_kernel(const float* __restrict__ xyz,
                        const float* __restrict__ sflow,
                        const int* __restrict__ rf,
                        const float4* __restrict__ bbox,
                        const u32* __restrict__ meta,
                        const float4* __restrict__ pts,
                        float* __restrict__ out,
                        int N, int M, int bpB) {
    __shared__ u64 mergeK[GROUPS_PER_BLOCK * KNN * 64];   // slice-1 publish, 10 KB

    const int tid   = threadIdx.x;
    const int lane  = tid & 63;
    const int wid   = tid >> 6;
    const int slice = __builtin_amdgcn_readfirstlane(wid & 1);   // uniform SGPR
    const int gid   = wid >> 1;                                  // group in block
    const int g     = blockIdx.x * GROUPS_PER_BLOCK + gid;       // global group
    const int b     = g / bpB;
    const int n     = (g % bpB) * 64 + lane;                     // N % 64 == 0

    const float inv = get_inv_sigma(rf);
    const float* qb = xyz + (size_t)b * 3 * N;
    const float qx = qb[n] * inv;
    const float qy = qb[N + n] * inv;
    const float qz = qb[2 * N + n] * inv;
    const float qq = fmaf(qx, qx, fmaf(qy, qy, qz * qz));

    const float4 o   = bbox[2 * b];
    const float invh = bbox[2 * b + 1].x;
    const float h    = o.w;
    int qcx, qcy, qcz; cell_of(qx, qy, qz, o, invh, qcx, qcy, qcz);

    const u32* mb = meta + b * G3;
    const float4* pb = pts + (size_t)b * M;

    u64 k0 = KEY_INIT, k1 = KEY_INIT, k2 = KEY_INIT, k3 = KEY_INIT, k4 = KEY_INIT;
    bool done = false;
    const float margin = 1e-3f + 1e-5f * qq;   // >> fp error of the d2 formula
    int stripe = 0;                            // uniform cell->slice parity counter

    for (int r = 0; r <= G && __any(!done); ++r) {
        for (int dz = -r; dz <= r; ++dz)
        for (int dy = -r; dy <= r; ++dy)
        for (int dx = -r; dx <= r; ++dx) {
            if (r > 0 && abs(dx) < r && abs(dy) < r && abs(dz) < r) continue;
            const int par = stripe & 1; ++stripe;          // uniform
            if (par != slice) continue;                    // uniform skip
            if (done) continue;                            // per-lane predication
            const int cx = qcx + dx, cy = qcy + dy, cz = qcz + dz;
            if ((u32)cx >= G || (u32)cy >= G || (u32)cz >= G) continue;
            const u32 mc = mb[(cz * G + cy) * G + cx];
            const u32 cnt = mc & 8191u;
            const u32 st  = mc >> 13;
            u32 i = 0;
            for (; i + 2 <= cnt; i += 2) {                 // 2x unroll: overlap gathers
                const float4 pa = pb[st + i];
                const float4 pc = pb[st + i + 1];
                PROC_CAND(pa)
                PROC_CAND(pc)
            }
            if (i < cnt) { const float4 pa = pb[st + i]; PROC_CAND(pa) }
        }
        if (!done) {
            // deterministic per-lane stop: own slice-local 5th-best is an
            // upper bound of global d5^2; unscanned cells (ring > r) are
            // >= r*h away.
            const float own = __uint_as_float((u32)(k4 >> 32));
            const float bound = (float)r * h;
            done = (own < bound * bound - margin);
        }
    }

    if (slice == 1) {
        mergeK[(gid * KNN + 0) * 64 + lane] = k0;
        mergeK[(gid * KNN + 1) * 64 + lane] = k1;
        mergeK[(gid * KNN + 2) * 64 + lane] = k2;
        mergeK[(gid * KNN + 3) * 64 + lane] = k3;
        mergeK[(gid * KNN + 4) * 64 + lane] = k4;
    }
    __syncthreads();

    if (slice == 0) {
#pragma unroll
        for (int k = 0; k < KNN; ++k) {
            u64 c = mergeK[(gid * KNN + k) * 64 + lane];
            CEK_FULL(k0, c) CEK_FULL(k1, c) CEK_FULL(k2, c) CEK_FULL(k3, c)
            CEK_LAST(k4, c)
        }
        const float d0 = sqrtf(__uint_as_float((u32)(k0 >> 32)));
        const float d1 = sqrtf(__uint_as_float((u32)(k1 >> 32)));
        const float d2 = sqrtf(__uint_as_float((u32)(k2 >> 32)));
        const float d3 = sqrtf(__uint_as_float((u32)(k3 >> 32)));
        const float d4 = sqrtf(__uint_as_float((u32)(k4 >> 32)));
        const float w0 = expf(d0 - d0);
        const float w1 = expf(d0 - d1);
        const float w2 = expf(d0 - d2);
        const float w3 = expf(d0 - d3);
        const float w4 = expf(d0 - d4);
        const float inv_wsum = 1.0f / (w0 + w1 + w2 + w3 + w4);

        const u32 i0 = (u32)k0, i1 = (u32)k1, i2 = (u32)k2, i3 = (u32)k3, i4 = (u32)k4;
        const float* fb = sflow + (size_t)b * 3 * M;
        float ax = 0.f, ay = 0.f, az = 0.f;
        ax = fmaf(w0, fb[i0], ax); ay = fmaf(w0, fb[M + i0], ay); az = fmaf(w0, fb[2 * M + i0], az);
        ax = fmaf(w1, fb[i1], ax); ay = fmaf(w1, fb[M + i1], ay); az = fmaf(w1, fb[2 * M + i1], az);
        ax = fmaf(w2, fb[i2], ax); ay = fmaf(w2, fb[M + i2], ay); az = fmaf(w2, fb[2 * M + i2], az);
        ax = fmaf(w3, fb[i3], ax); ay = fmaf(w3, fb[M + i3], ay); az = fmaf(w3, fb[2 * M + i3], az);
        ax = fmaf(w4, fb[i4], ax); ay = fmaf(w4, fb[M + i4], ay); az = fmaf(w4, fb[2 * M + i4], az);

        float* ob = out + (size_t)b * 3 * N;
        ob[n]         = ax * inv_wsum;
        ob[N + n]     = ay * inv_wsum;
        ob[2 * N + n] = az * inv_wsum;
    }
}

// ---------------- brute-force fallback (r3 structure, no workspace) ----------------

#define CE_FULL(k, ki, c, ci)                          \
    {                                                  \
        const bool sw = (c) < (k);                     \
        const float vmn = fminf(k, c);                 \
        const float vmx = fmaxf(k, c);                 \
        const u32 nki = sw ? (ci) : (ki);              \
        const u32 nci = sw ? (ki) : (ci);              \
        (k) = vmn; (c) = vmx; (ki) = nki; (ci) = nci;  \
    }
#define CE_LAST(k, ki, c, ci)                          \
    {                                                  \
        const bool sw = (c) < (k);                     \
        (ki) = sw ? (ci) : (ki);                       \
        (k) = fminf(k, c);                             \
    }

#define BSLICES 8
__global__ __launch_bounds__(512)
void brute_kernel(const float* __restrict__ xyz, const float* __restrict__ sxyz,
                  const float* __restrict__ sflow, const int* __restrict__ rf,
                  float* __restrict__ out, int N, int M, int bpB) {
    __shared__ float sval_d[BSLICES * KNN * 64];
    __shared__ u32   sval_i[BSLICES * KNN * 64];
    const int tid = threadIdx.x, lane = tid & 63, wid = tid >> 6;
    const int swid = __builtin_amdgcn_readfirstlane(wid);
    const int b = blockIdx.x / bpB;
    const int n = (blockIdx.x % bpB) * 64 + lane;
    const float inv = get_inv_sigma(rf);
    const float* qb = xyz + (size_t)b * 3 * N;
    const float qx = qb[n] * inv, qy = qb[N + n] * inv, qz = qb[2 * N + n] * inv;
    const float qq = fmaf(qx, qx, fmaf(qy, qy, qz * qz));
    const int CH = M / BSLICES, j0 = swid * CH;
    const float* sb = sxyz + (size_t)b * 3 * M;
    float e0 = 1e30f, e1 = 1e30f, e2 = 1e30f, e3 = 1e30f, e4 = 1e30f;
    u32 i0 = 0, i1 = 0, i2 = 0, i3 = 0, i4 = 0;
    for (int j = 0; j < CH; ++j) {
        const float px = sb[j0 + j] * inv;
        const float py = sb[M + j0 + j] * inv;
        const float pz = sb[2 * M + j0 + j] * inv;
        const float pw = fmaf(px, px, fmaf(py, py, pz * pz));
        float t = qx * px; t = fmaf(qy, py, t); t = fmaf(qz, pz, t);
        float c = fmaf(-2.0f, t, pw);
        u32 ci = (u32)(j0 + j);
        CE_FULL(e0, i0, c, ci) CE_FULL(e1, i1, c, ci) CE_FULL(e2, i2, c, ci)
        CE_FULL(e3, i3, c, ci) CE_LAST(e4, i4, c, ci)
    }
    sval_d[(wid * KNN + 0) * 64 + lane] = e0;  sval_i[(wid * KNN + 0) * 64 + lane] = i0;
    sval_d[(wid * KNN + 1) * 64 + lane] = e1;  sval_i[(wid * KNN + 1) * 64 + lane] = i1;
    sval_d[(wid * KNN + 2) * 64 + lane] = e2;  sval_i[(wid * KNN + 2) * 64 + lane] = i2;
    sval_d[(wid * KNN + 3) * 64 + lane] = e3;  sval_i[(wid * KNN + 3) * 64 + lane] = i3;
    sval_d[(wid * KNN + 4) * 64 + lane] = e4;  sval_i[(wid * KNN + 4) * 64 + lane] = i4;
    __syncthreads();
    if (wid == 0) {
        float m0 = 1e30f, m1 = 1e30f, m2 = 1e30f, m3 = 1e30f, m4 = 1e30f;
        u32 g0 = 0, g1 = 0, g2 = 0, g3 = 0, g4 = 0;
#pragma unroll
        for (int w = 0; w < BSLICES; ++w)
#pragma unroll
            for (int k = 0; k < KNN; ++k) {
                float c = sval_d[(w * KNN + k) * 64 + lane];
                u32 ci = sval_i[(w * KNN + k) * 64 + lane];
                CE_FULL(m0, g0, c, ci) CE_FULL(m1, g1, c, ci) CE_FULL(m2, g2, c, ci)
                CE_FULL(m3, g3, c, ci) CE_LAST(m4, g4, c, ci)
            }
        const float d0 = sqrtf(fmaxf(m0 + qq, 1e-12f));
        const float d1 = sqrtf(fmaxf(m1 + qq, 1e-12f));
        const float d2 = sqrtf(fmaxf(m2 + qq, 1e-12f));
        const float d3 = sqrtf(fmaxf(m3 + qq, 1e-12f));
        const float d4 = sqrtf(fmaxf(m4 + qq, 1e-12f));
        const float w0 = expf(d0 - d0), w1 = expf(d0 - d1), w2 = expf(d0 - d2);
        const float w3 = expf(d0 - d3), w4 = expf(d0 - d4);
        const float inv_wsum = 1.0f / (w0 + w1 + w2 + w3 + w4);
        const float* fb = sflow + (size_t)b * 3 * M;
        float ax = 0.f, ay = 0.f, az = 0.f;
        ax = fmaf(w0, fb[g0], ax); ay = fmaf(w0, fb[M + g0], ay); az = fmaf(w0, fb[2 * M + g0], az);
        ax = fmaf(w1, fb[g1], ax); ay = fmaf(w1, fb[M + g1], ay); az = fmaf(w1, fb[2 * M + g1], az);
        ax = fmaf(w2, fb[g2], ax); ay = fmaf(w2, fb[M + g2], ay); az = fmaf(w2, fb[2 * M + g2], az);
        ax = fmaf(w3, fb[g3], ax); ay = fmaf(w3, fb[M + g3], ay); az = fmaf(w3, fb[2 * M + g3], az);
        ax = fmaf(w4, fb[g4], ax); ay = fmaf(w4, fb[M + g4], ay); az = fmaf(w4, fb[2 * M + g4], az);
        float* ob = out + (size_t)b * 3 * N;
        ob[n] = ax * inv_wsum;
        ob[N + n] = ay * inv_wsum;
        ob[2 * N + n] = az * inv_wsum;
    }
}

extern "C" void kernel_launch(void* const* d_in, const int* in_sizes, int n_in,
                              void* d_out, int out_size, void* d_ws, size_t ws_size,
                              hipStream_t stream) {
    const float* xyz   = (const float*)d_in[0];
    const float* sxyz  = (const float*)d_in[1];
    const float* sflow = (const float*)d_in[2];
    const int*   rf    = (const int*)d_in[3];
    // d_in[4] = K; fixed at 5 (KNN).

    const int B = 4;
    const int N = in_sizes[0] / (3 * B);    // 16384
    const int M = in_sizes[1] / (3 * B);    // 4096
    float* out = (float*)d_out;
    const int bpB = N / 64;                 // 256

    // workspace layout
    const size_t bboxBytes = (size_t)B * 2 * sizeof(float4);
    const size_t metaBytes = (size_t)B * G3 * sizeof(u32);              // 64 KB
    const size_t ptsBytes  = (size_t)B * M * sizeof(float4);            // 256 KB
    const size_t need = bboxBytes + 2 * metaBytes + ptsBytes;

    if (ws_size >= need && M <= 8191) {
        char* w = (char*)d_ws;
        float4* bbox  = (float4*)w;                       w += bboxBytes;
        u32*    meta  = (u32*)w;                          w += metaBytes;
        u32*    cursor= (u32*)w;                          w += metaBytes;
        float4* pts   = (float4*)w;

        zero_bbox_kernel<<<dim3(B), dim3(256), 0, stream>>>(sxyz, rf, M, bbox, meta, cursor);
        count_kernel<<<dim3((B * M + 255) / 256), dim3(256), 0, stream>>>(sxyz, rf, M, B * M, bbox, meta);
        scan_kernel<<<dim3(B), dim3(256), 0, stream>>>(meta, cursor);
        scatter_kernel<<<dim3((B * M + 255) / 256), dim3(256), 0, stream>>>(sxyz, rf, M, B * M, bbox, cursor, pts);
        const int nGroups = B * bpB;                       // 1024
        grid_search_kernel<<<dim3(nGroups / GROUPS_PER_BLOCK), dim3(SBLOCK), 0, stream>>>(
            xyz, sflow, rf, bbox, meta, pts, out, N, M, bpB);
    } else {
        brute_kernel<<<dim3(B * bpB), dim3(512), 0, stream>>>(xyz, sxyz, sflow, rf, out, N, M, bpB);
    }
}